// Round 5
// baseline (264.719 us; speedup 1.0000x reference)
//
#include <hip/hip_runtime.h>
#include <math.h>

// Round 5: back to 3 dispatches (round-3 structure) with occupancy fixed.
// Round-4 lesson: 256-block fused kernel = 1 wave/SIMD = latency-bound disaster
// (116 us @ 193 GB/s). Fix: high-occupancy separate dispatches.
//   D1: memset 36.5 KB accumulators
//   D2: colsumsq (512 blocks, 16 rows/thread) + CE (32 blocks)  [8+ waves/CU]
//   D3: gemv (2048 blocks = row x half-row) = 32 waves/CU, full occupancy;
//       last-done block finalizes (spin on done counter, proven in r3/r4).
// Identity: sum(G) = ||sum_n Hn[n]||^2, trace(G) = N  =>  no N x N Gram.

#define N_COLS 8192
#define D_ROWS 1024
#define B_ROWS 8192
#define CSS_BLOCKS 512     // 8 col-groups x 64 row-groups (16 rows)
#define CE_BLOCKS  32
#define GEMV_BLOCKS (D_ROWS * 2)   // (row d, half h)
#define EPSQ 1e-24f

// ---------------------------------------------------------------------------
__device__ inline float block_reduce_sum_256(float v) {
    #pragma unroll
    for (int off = 32; off > 0; off >>= 1) v += __shfl_down(v, off, 64);
    __shared__ float sm[4];
    int lane = threadIdx.x & 63;
    int wid  = threadIdx.x >> 6;
    if (lane == 0) sm[wid] = v;
    __syncthreads();
    if (threadIdx.x < 4) {
        v = sm[threadIdx.x];
        v += __shfl_down(v, 2, 64);
        v += __shfl_down(v, 1, 64);
    }
    return v;
}

// ---------------------------------------------------------------------------
// Blocks [0,512): column sums of squares (16 rows x 1024 cols panel each).
// Blocks [512,544): CE over [B,2] logits.
__global__ __launch_bounds__(256)
void colsumsq_ce_kernel(const float* __restrict__ H,
                        const float* __restrict__ logits,
                        const int* __restrict__ labels,
                        float* __restrict__ norms2,
                        float* __restrict__ ce_acc) {
    const int t = threadIdx.x;
    if (blockIdx.x < CSS_BLOCKS) {
        const int cg = blockIdx.x & 7;
        const int rg = blockIdx.x >> 3;
        const int col4 = cg * 256 + t;
        const int row0 = rg * 16;
        const float4* __restrict__ H4 = (const float4*)H;
        float ax = 0.f, ay = 0.f, az = 0.f, aw = 0.f;
        #pragma unroll
        for (int r = 0; r < 16; ++r) {
            float4 v = H4[(size_t)(row0 + r) * (N_COLS / 4) + col4];
            ax = fmaf(v.x, v.x, ax);
            ay = fmaf(v.y, v.y, ay);
            az = fmaf(v.z, v.z, az);
            aw = fmaf(v.w, v.w, aw);
        }
        const int col = col4 * 4;
        atomicAdd(&norms2[col + 0], ax);
        atomicAdd(&norms2[col + 1], ay);
        atomicAdd(&norms2[col + 2], az);
        atomicAdd(&norms2[col + 3], aw);
    } else {
        const int b = (blockIdx.x - CSS_BLOCKS) * 256 + t;   // covers B exactly
        float2 x = ((const float2*)logits)[b];
        float m = fmaxf(x.x, x.y);
        float lse = m + __logf(__expf(x.x - m) + __expf(x.y - m));
        float s = block_reduce_sum_256(lse - ((labels[b] == 0) ? x.x : x.y));
        if (t == 0) atomicAdd(ce_acc, s);
    }
}

// ---------------------------------------------------------------------------
// 2048 blocks: block b handles row d = b>>1, half h = b&1 (1024 float4 cols).
// Each thread: 4 float4 H loads + weights; wave-reduce -> atomicAdd s_vec[d].
// Last finished block computes the final scalar.
__global__ __launch_bounds__(256)
void gemv_finalize_kernel(const float* __restrict__ H,
                          const float* __restrict__ norms2,
                          float* __restrict__ s_vec,
                          const float* __restrict__ ce_acc,
                          unsigned int* __restrict__ done_cnt,
                          float* __restrict__ out) {
    const int t = threadIdx.x;
    const int d = blockIdx.x >> 1;
    const int h = blockIdx.x & 1;
    const float4* __restrict__ Hrow = (const float4*)(H + (size_t)d * N_COLS);
    const float4* __restrict__ n24  = (const float4*)norms2;
    float p = 0.f;
    #pragma unroll
    for (int k = 0; k < 4; ++k) {
        const int i = h * 1024 + k * 256 + t;
        float4 v  = Hrow[i];
        float4 n2 = n24[i];
        p = fmaf(v.x, rsqrtf(fmaxf(n2.x, EPSQ)), p);
        p = fmaf(v.y, rsqrtf(fmaxf(n2.y, EPSQ)), p);
        p = fmaf(v.z, rsqrtf(fmaxf(n2.z, EPSQ)), p);
        p = fmaf(v.w, rsqrtf(fmaxf(n2.w, EPSQ)), p);
    }
    #pragma unroll
    for (int off = 32; off > 0; off >>= 1) p += __shfl_down(p, off, 64);
    if ((t & 63) == 0) atomicAdd(&s_vec[d], p);

    // ---- completion count; last block finalizes ----
    __threadfence();
    __syncthreads();
    __shared__ bool last;
    if (t == 0) {
        unsigned int old = atomicAdd(done_cnt, 1u);
        last = (old == GEMV_BLOCKS - 1);
    }
    __syncthreads();
    if (!last) return;
    __threadfence();   // acquire: s_vec atomics are all globally visible

    float sq = 0.f;
    #pragma unroll
    for (int i = 0; i < 4; ++i) {
        float s = s_vec[t + i * 256];
        sq = fmaf(s, s, sq);
    }
    float s2 = block_reduce_sum_256(sq);
    if (t == 0) {
        float ce = *(volatile float*)ce_acc;
        double reg = ((double)s2 - (double)N_COLS) * 0.5
                     / ((double)N_COLS * (double)(N_COLS - 1));
        out[0] = (float)((double)ce / (double)B_ROWS + reg);
    }
}

// ---------------------------------------------------------------------------
extern "C" void kernel_launch(void* const* d_in, const int* in_sizes, int n_in,
                              void* d_out, int out_size, void* d_ws, size_t ws_size,
                              hipStream_t stream) {
    const float* outputs = (const float*)d_in[0];   // [B, 2] f32
    const int*   labels  = (const int*)d_in[1];     // [B]
    const float* H       = (const float*)d_in[2];   // [D, N] f32
    float* out = (float*)d_out;

    // ws layout (floats): norms2[8192] | s_vec[1024] | ce_acc[1] | pad | done[1]
    float* norms2 = (float*)d_ws;
    float* s_vec  = norms2 + N_COLS;
    float* ce_acc = s_vec + D_ROWS;
    unsigned int* done_cnt = (unsigned int*)(ce_acc + 8);

    hipMemsetAsync(d_ws, 0, (N_COLS + D_ROWS + 16) * sizeof(float), stream);

    colsumsq_ce_kernel<<<CSS_BLOCKS + CE_BLOCKS, 256, 0, stream>>>(
        H, outputs, labels, norms2, ce_acc);
    gemv_finalize_kernel<<<GEMV_BLOCKS, 256, 0, stream>>>(
        H, norms2, s_vec, ce_acc, done_cnt, out);
}

// Round 6
// 117.318 us; speedup vs baseline: 2.2564x; 2.2564x over previous
//
#include <hip/hip_runtime.h>
#include <math.h>

// Round 6: round-5 structure minus the __threadfence disaster.
// Evidence: r3 (fences on lane 0 only) gemv < 43 us; r5 (block-wide fences)
// gemv = 186 us @ 92 GB/s, VALUBusy 0.9% -> agent-scope fence = per-XCD L2
// writeback/invalidate storm on gfx950. Replacement protocol:
//   release: s_waitcnt vmcnt(0) (drain own atomics, no cache flush) + barrier
//   acquire: atomicAdd(p, 0.0f) coherent-RMW reads (r3-proven).
// Identity: sum(G) = ||sum_n Hn[n]||^2, trace(G) = N  =>  no N x N Gram.
//   D1: memset 37 KB accumulators
//   D2: colsumsq (512 blocks, 16 rows each) + CE (32 blocks)
//   D3: gemv (2048 blocks = row x half) + last-done-block finalize

#define N_COLS 8192
#define D_ROWS 1024
#define B_ROWS 8192
#define CSS_BLOCKS 512
#define CE_BLOCKS  32
#define GEMV_BLOCKS (D_ROWS * 2)
#define EPSQ 1e-24f

// ---------------------------------------------------------------------------
__device__ inline float block_reduce_sum_256(float v) {
    #pragma unroll
    for (int off = 32; off > 0; off >>= 1) v += __shfl_down(v, off, 64);
    __shared__ float sm[4];
    int lane = threadIdx.x & 63;
    int wid  = threadIdx.x >> 6;
    if (lane == 0) sm[wid] = v;
    __syncthreads();
    if (threadIdx.x < 4) {
        v = sm[threadIdx.x];
        v += __shfl_down(v, 2, 64);
        v += __shfl_down(v, 1, 64);
    }
    return v;
}

// ---------------------------------------------------------------------------
// Blocks [0,512): column sums of squares (16 rows x 1024 cols panel each).
// Blocks [512,544): CE over [B,2] logits.
__global__ __launch_bounds__(256)
void colsumsq_ce_kernel(const float* __restrict__ H,
                        const float* __restrict__ logits,
                        const int* __restrict__ labels,
                        float* __restrict__ norms2,
                        float* __restrict__ ce_acc) {
    const int t = threadIdx.x;
    if (blockIdx.x < CSS_BLOCKS) {
        const int cg = blockIdx.x & 7;
        const int rg = blockIdx.x >> 3;
        const int col4 = cg * 256 + t;
        const int row0 = rg * 16;
        const float4* __restrict__ H4 = (const float4*)H;
        float ax = 0.f, ay = 0.f, az = 0.f, aw = 0.f;
        #pragma unroll
        for (int r = 0; r < 16; ++r) {
            float4 v = H4[(size_t)(row0 + r) * (N_COLS / 4) + col4];
            ax = fmaf(v.x, v.x, ax);
            ay = fmaf(v.y, v.y, ay);
            az = fmaf(v.z, v.z, az);
            aw = fmaf(v.w, v.w, aw);
        }
        const int col = col4 * 4;
        atomicAdd(&norms2[col + 0], ax);
        atomicAdd(&norms2[col + 1], ay);
        atomicAdd(&norms2[col + 2], az);
        atomicAdd(&norms2[col + 3], aw);
    } else {
        const int b = (blockIdx.x - CSS_BLOCKS) * 256 + t;   // covers B exactly
        float2 x = ((const float2*)logits)[b];
        float m = fmaxf(x.x, x.y);
        float lse = m + __logf(__expf(x.x - m) + __expf(x.y - m));
        float s = block_reduce_sum_256(lse - ((labels[b] == 0) ? x.x : x.y));
        if (t == 0) atomicAdd(ce_acc, s);
    }
}

// ---------------------------------------------------------------------------
// 2048 blocks: block b handles row d = b>>1, half h = b&1 (1024 float4 cols).
// norms2 is visible via the kernel-boundary dependency (plain loads fine, r3).
__global__ __launch_bounds__(256)
void gemv_finalize_kernel(const float* __restrict__ H,
                          const float* __restrict__ norms2,
                          float* __restrict__ s_vec,
                          float* __restrict__ ce_acc,
                          unsigned int* __restrict__ done_cnt,
                          float* __restrict__ out) {
    const int t = threadIdx.x;
    const int d = blockIdx.x >> 1;
    const int h = blockIdx.x & 1;
    const float4* __restrict__ Hrow = (const float4*)(H + (size_t)d * N_COLS);
    const float4* __restrict__ n24  = (const float4*)norms2;
    float p = 0.f;
    #pragma unroll
    for (int k = 0; k < 4; ++k) {
        const int i = h * 1024 + k * 256 + t;
        float4 v  = Hrow[i];
        float4 n2 = n24[i];
        p = fmaf(v.x, rsqrtf(fmaxf(n2.x, EPSQ)), p);
        p = fmaf(v.y, rsqrtf(fmaxf(n2.y, EPSQ)), p);
        p = fmaf(v.z, rsqrtf(fmaxf(n2.z, EPSQ)), p);
        p = fmaf(v.w, rsqrtf(fmaxf(n2.w, EPSQ)), p);
    }
    #pragma unroll
    for (int off = 32; off > 0; off >>= 1) p += __shfl_down(p, off, 64);
    if ((t & 63) == 0) atomicAdd(&s_vec[d], p);   // device-scope, lands at LLC

    // ---- release: drain this wave's outstanding VMEM (incl. the atomic),
    // no cache writeback. Then one done-count per block.
    asm volatile("s_waitcnt vmcnt(0)" ::: "memory");
    __syncthreads();
    __shared__ bool last;
    if (t == 0) last = (atomicAdd(done_cnt, 1u) == GEMV_BLOCKS - 1);
    __syncthreads();
    if (!last) return;

    // ---- finalize on the last block; coherent reads via atomic RMW ----
    float sq = 0.f;
    #pragma unroll
    for (int i = 0; i < 4; ++i) {
        float s = atomicAdd(&s_vec[t + i * 256], 0.0f);
        sq = fmaf(s, s, sq);
    }
    float s2 = block_reduce_sum_256(sq);
    if (t == 0) {
        float ce = atomicAdd(ce_acc, 0.0f);
        double reg = ((double)s2 - (double)N_COLS) * 0.5
                     / ((double)N_COLS * (double)(N_COLS - 1));
        out[0] = (float)((double)ce / (double)B_ROWS + reg);
    }
}

// ---------------------------------------------------------------------------
extern "C" void kernel_launch(void* const* d_in, const int* in_sizes, int n_in,
                              void* d_out, int out_size, void* d_ws, size_t ws_size,
                              hipStream_t stream) {
    const float* outputs = (const float*)d_in[0];   // [B, 2] f32
    const int*   labels  = (const int*)d_in[1];     // [B]
    const float* H       = (const float*)d_in[2];   // [D, N] f32
    float* out = (float*)d_out;

    // ws layout (floats): norms2[8192] | s_vec[1024] | ce_acc[1] | pad | done[1]
    float* norms2 = (float*)d_ws;
    float* s_vec  = norms2 + N_COLS;
    float* ce_acc = s_vec + D_ROWS;
    unsigned int* done_cnt = (unsigned int*)(ce_acc + 8);

    hipMemsetAsync(d_ws, 0, (N_COLS + D_ROWS + 16) * sizeof(float), stream);

    colsumsq_ce_kernel<<<CSS_BLOCKS + CE_BLOCKS, 256, 0, stream>>>(
        H, outputs, labels, norms2, ce_acc);
    gemv_finalize_kernel<<<GEMV_BLOCKS, 256, 0, stream>>>(
        H, norms2, s_vec, ce_acc, done_cnt, out);
}